// Round 2
// baseline (838.816 us; speedup 1.0000x reference)
//
#include <hip/hip_runtime.h>

typedef unsigned short u16;
typedef short bf16x8 __attribute__((ext_vector_type(8)));
typedef float f32x4 __attribute__((ext_vector_type(4)));

__device__ __forceinline__ float bf2f(unsigned v) { return __uint_as_float(v << 16); }
__device__ __forceinline__ u16 f2bf(float f) {
    unsigned u = __float_as_uint(f);
    return (u16)((u + 0x7fffu + ((u >> 16) & 1u)) >> 16);
}

// ---- async global->LDS, width 16B per lane, dest = wave base + lane*16 ----
__device__ __forceinline__ void gload_lds16(const void* g, void* l) {
    __builtin_amdgcn_global_load_lds(
        (const __attribute__((address_space(1))) unsigned int*)g,
        (__attribute__((address_space(3))) unsigned int*)l, 16, 0, 0);
}

// LDS tile swizzle (both-sides): 64B rows of 4x16B granules; granule ^= (row>>1)&3.
// Stage side: global source granule = (lane&3) ^ ((lane>>3)&3)  (row = lane>>2).
// Read side:  granule = quad ^ ((c>>1)&3)                       (row = base16 + c).

// =====================================================================
// Bitmask: bit j of word w  <=>  adj[w*32 + j] > 0   (adj fp32)
__global__ __launch_bounds__(256) void k_mask(const float* __restrict__ adj,
                                              unsigned* __restrict__ mask) {
    int w = blockIdx.x * 256 + threadIdx.x;           // 524288 words
    const float4* q = (const float4*)(adj + (size_t)w * 32);
    unsigned bits = 0u;
#pragma unroll
    for (int i = 0; i < 8; i++) {
        float4 v = q[i];
        if (v.x > 0.f) bits |= (1u << (i * 4 + 0));
        if (v.y > 0.f) bits |= (1u << (i * 4 + 1));
        if (v.z > 0.f) bits |= (1u << (i * 4 + 2));
        if (v.w > 0.f) bits |= (1u << (i * 4 + 3));
    }
    mask[w] = bits;
}

// =====================================================================
// Transpose [K,128] fp32 -> [128,K] bf16 per matrix (batch = blockIdx.z)
__global__ void k_trans(const float* __restrict__ in, u16* __restrict__ out, int K) {
    __shared__ float t[32][33];
    const float* src = in + (size_t)blockIdx.z * K * 128;
    u16* dst = out + (size_t)blockIdx.z * K * 128;
    int k0 = blockIdx.x * 32, n0 = blockIdx.y * 32;
    int tx = threadIdx.x, ty = threadIdx.y;           // 32 x 8
#pragma unroll
    for (int i = 0; i < 32; i += 8) t[ty + i][tx] = src[(size_t)(k0 + ty + i) * 128 + n0 + tx];
    __syncthreads();
#pragma unroll
    for (int i = 0; i < 32; i += 8) dst[(size_t)(n0 + ty + i) * K + k0 + tx] = f2bf(t[tx][ty + i]);
}

// =====================================================================
// fp32 -> bf16 elementwise (entity embedding), 4 elems/thread
__global__ __launch_bounds__(256) void k_cvt(const float* __restrict__ in,
                                             u16* __restrict__ out) {
    int t = blockIdx.x * 256 + threadIdx.x;
    float4 v = ((const float4*)in)[t];
    uint2 o;
    o.x = (unsigned)f2bf(v.x) | ((unsigned)f2bf(v.y) << 16);
    o.y = (unsigned)f2bf(v.z) | ((unsigned)f2bf(v.w) << 16);
    ((uint2*)out)[t] = o;
}

// =====================================================================
// Projection: Wh = x @ W_h  (M=4096, N=128, K=Fin). X bf16, WT bf16 [n][k],
// avec fp32. Writes WhT[n][j] bf16 and f1/f2 fp32.
__global__ __launch_bounds__(1024, 4) void k_proj(const u16* __restrict__ X,
                                                  const u16* __restrict__ WT,
                                                  const float* __restrict__ avec,
                                                  u16* __restrict__ WhT,
                                                  float* __restrict__ f1,
                                                  float* __restrict__ f2, int Fin) {
    __shared__ u16 As[2][64 * 32];    // 8 KB  [row][k] (swizzled granules)
    __shared__ u16 Bs[2][128 * 32];   // 16 KB [n][k]   (swizzled granules)
    __shared__ float fpart[4][64][2]; // per-colgroup f1/f2 partials
    const int tid = threadIdx.x;
    const int wv = tid >> 6, lane = tid & 63;
    const int rg = wv & 3, cg = wv >> 2;
    const int c = lane & 15, quad = lane >> 4;
    const int bofs = (quad ^ ((c >> 1) & 3)) * 8;     // swizzled read granule
    const int h = blockIdx.y;
    const int j0 = blockIdx.x * 64;
    const u16* Wp = WT + (size_t)h * 128 * Fin;
    const int sgr = ((lane & 3) ^ ((lane >> 3) & 3)) * 8;  // swizzled source granule

#define PROJ_STAGE(buf, kb)                                                              \
    do {                                                                                 \
        if (cg == 0)                                                                     \
            gload_lds16(X + (size_t)(j0 + rg * 16 + (lane >> 2)) * Fin + (kb) + sgr,     \
                        (void*)&As[buf][rg * 16 * 32]);                                  \
        else if (cg <= 2)                                                                \
            gload_lds16(Wp + (size_t)((cg - 1) * 64 + rg * 16 + (lane >> 2)) * Fin + (kb) + sgr, \
                        (void*)&Bs[buf][((cg - 1) * 64 + rg * 16) * 32]);                \
    } while (0)

    PROJ_STAGE(0, 0);
    __syncthreads();

    f32x4 acc[2];
    acc[0] = (f32x4){0.f, 0.f, 0.f, 0.f};
    acc[1] = (f32x4){0.f, 0.f, 0.f, 0.f};

    int it = 0;
    for (int kb = 0; kb < Fin; kb += 32, it++) {
        const int cur = it & 1;
        if (kb + 32 < Fin) PROJ_STAGE(cur ^ 1, kb + 32);
        bf16x8 av = *(const bf16x8*)&As[cur][(rg * 16 + c) * 32 + bofs];
#pragma unroll
        for (int e = 0; e < 2; e++) {
            bf16x8 bv = *(const bf16x8*)&Bs[cur][((cg * 2 + e) * 16 + c) * 32 + bofs];
            acc[e] = __builtin_amdgcn_mfma_f32_16x16x32_bf16(av, bv, acc[e], 0, 0, 0);
        }
        __syncthreads();
    }

    // epilogue: C row = rg*16+quad*4+r, col n = (cg*2+e)*16+c
    u16* Wo = WhT + (size_t)h * 128 * 4096;
    const float* ah = avec + h * 256;
    float p1[4] = {0, 0, 0, 0}, p2[4] = {0, 0, 0, 0};
#pragma unroll
    for (int e = 0; e < 2; e++) {
        const int n = (cg * 2 + e) * 16 + c;
        float a1 = ah[n];
        float a2 = ah[128 + n];
        u16 w4[4];
#pragma unroll
        for (int r = 0; r < 4; r++) {
            float v = acc[e][r];
            w4[r] = f2bf(v);
            p1[r] += v * a1;
            p2[r] += v * a2;
        }
        uint2 pk;
        pk.x = (unsigned)w4[0] | ((unsigned)w4[1] << 16);
        pk.y = (unsigned)w4[2] | ((unsigned)w4[3] << 16);
        *(uint2*)&Wo[(size_t)n * 4096 + j0 + rg * 16 + quad * 4] = pk;
    }
#pragma unroll
    for (int off = 1; off < 16; off <<= 1) {
#pragma unroll
        for (int r = 0; r < 4; r++) {
            p1[r] += __shfl_xor(p1[r], off);
            p2[r] += __shfl_xor(p2[r], off);
        }
    }
    if (c == 0) {
#pragma unroll
        for (int r = 0; r < 4; r++) {
            fpart[cg][rg * 16 + quad * 4 + r][0] = p1[r];
            fpart[cg][rg * 16 + quad * 4 + r][1] = p2[r];
        }
    }
    __syncthreads();
    if (tid < 64) {
        float s1 = fpart[0][tid][0] + fpart[1][tid][0] + fpart[2][tid][0] + fpart[3][tid][0];
        float s2 = fpart[0][tid][1] + fpart[1][tid][1] + fpart[2][tid][1] + fpart[3][tid][1];
        f1[h * 4096 + j0 + tid] = s1;
        f2[h * 4096 + j0 + tid] = s2;
    }
}

// =====================================================================
// Fused masked softmax attention + ELU.
// 512 thr = 8 waves = 4 j-groups (1024 j each) x 2 row-groups (32 rows each),
// two 16-row A-fragments per wave.
// VALU diet vs previous version:
//  - exp factored out of the (i,j) loop: p = cond ? C1_i*E1_j : C2_i*E2_j
//    with E1/E2 precomputed per j (LDS), C1/C2/T per i (regs). Inner elem =
//    cmp + 2 cndmask + mul + and  (no exp2, no leakyrelu chain).
//  - mask applied via 8KB LUT: byte -> 8x {0xffff0000|0} truncation masks.
//  - row denominators via ones-MFMA (exact over the same truncated bf16 P).
//  - P(kb+1) computed BEFORE the barrier (depends only on E12/LUT/mask, not
//    on the double-buffered Bs) -> VALU overlaps MFMA(kb). Manual 2x unroll,
//    static ping-pong register states (no runtime indexing).
template <bool F32OUT>
__global__ __launch_bounds__(512, 2) void k_attn(const u16* __restrict__ WhT,
                                                 const float* __restrict__ f1g,
                                                 const float* __restrict__ f2g,
                                                 const unsigned char* __restrict__ maskb,
                                                 void* __restrict__ outp, int ostride) {
    __shared__ float E12[8192];            // 32 KB {E1_j, E2_j} interleaved
    __shared__ unsigned LUTM[256 * 8];     // 8 KB mask byte -> 8 AND-masks
    __shared__ u16 Bs[2][4][128 * 32];     // 64 KB double-buffered WhT tiles
    __shared__ float lpart[4][64];         // per-jgroup row denominators
    __shared__ float redmax[8];
    __shared__ float red[64 * 132];        // 33 KB fp32 acc reduce [i][n], pad 4

    const int tid = threadIdx.x;
    const int wv = tid >> 6, lane = tid & 63;
    const int jg = wv >> 1, rg = wv & 1;
    const int c = lane & 15, quad = lane >> 4;
    const int bofs = (quad ^ ((c >> 1) & 3)) * 8;          // swizzled read granule
    const int sgr = ((lane & 3) ^ ((lane >> 3) & 3)) * 8;  // swizzled source granule
    const int h = blockIdx.y;
    const int i0 = blockIdx.x * 64;
    const float LOG2E = 1.4426950408889634f;
    const float* f1h = f1g + h * 4096;
    const float* f2h = f2g + h * 4096;
    const u16* Wp = WhT + (size_t)h * 128 * 4096;

#define ATTN_STAGE(buf, kb)                                                              \
    do {                                                                                 \
        const int jb_ = jg * 1024 + (kb) * 32;                                           \
        _Pragma("unroll")                                                                \
        for (int e_ = 0; e_ < 4; e_++)                                                   \
            gload_lds16(Wp + (size_t)(rg * 64 + e_ * 16 + (lane >> 2)) * 4096 + jb_ + sgr, \
                        (void*)&Bs[buf][jg][(rg * 64 + e_ * 16) * 32]);                  \
    } while (0)

    // ---- prologue: load f2 (keep in regs), build LUT, stage tile 0 ----
    float f2p[8];
    float mymax = -3.0e38f;
    {
        float4 v0 = ((const float4*)f2h)[tid * 2];
        float4 v1 = ((const float4*)f2h)[tid * 2 + 1];
        f2p[0] = v0.x * LOG2E; f2p[1] = v0.y * LOG2E;
        f2p[2] = v0.z * LOG2E; f2p[3] = v0.w * LOG2E;
        f2p[4] = v1.x * LOG2E; f2p[5] = v1.y * LOG2E;
        f2p[6] = v1.z * LOG2E; f2p[7] = v1.w * LOG2E;
#pragma unroll
        for (int k = 0; k < 8; k++) mymax = fmaxf(mymax, f2p[k]);
    }
    if (tid < 256) {
        uint4 a, b;
        a.x = (tid & 1)   ? 0xffff0000u : 0u;
        a.y = (tid & 2)   ? 0xffff0000u : 0u;
        a.z = (tid & 4)   ? 0xffff0000u : 0u;
        a.w = (tid & 8)   ? 0xffff0000u : 0u;
        b.x = (tid & 16)  ? 0xffff0000u : 0u;
        b.y = (tid & 32)  ? 0xffff0000u : 0u;
        b.z = (tid & 64)  ? 0xffff0000u : 0u;
        b.w = (tid & 128) ? 0xffff0000u : 0u;
        *(uint4*)&LUTM[tid * 8] = a;
        *(uint4*)&LUTM[tid * 8 + 4] = b;
    }
    ATTN_STAGE(0, 0);

#pragma unroll
    for (int off = 1; off < 64; off <<= 1) mymax = fmaxf(mymax, __shfl_xor(mymax, off));
    if (lane == 0) redmax[wv] = mymax;
    __syncthreads();
    float F2MAX = redmax[0];
#pragma unroll
    for (int i = 1; i < 8; i++) F2MAX = fmaxf(F2MAX, redmax[i]);

    // write E12 (each thread owns j = tid*8 .. tid*8+7)
    {
        const int j0w = tid * 8;
#pragma unroll
        for (int k = 0; k < 8; k += 2) {
            float d0 = f2p[k] - F2MAX, d1 = f2p[k + 1] - F2MAX;
            float4 w;
            w.x = __builtin_amdgcn_exp2f(d0);
            w.y = __builtin_amdgcn_exp2f(0.2f * d0);
            w.z = __builtin_amdgcn_exp2f(d1);
            w.w = __builtin_amdgcn_exp2f(0.2f * d1);
            *(float4*)&E12[2 * (j0w + k)] = w;
        }
    }

    // per-i constants (two fragment rows per thread)
    const int iloc0 = rg * 32 + c;
    const int iloc1 = iloc0 + 16;
    const float rf1a = f1h[i0 + iloc0] * LOG2E;
    const float rf1b = f1h[i0 + iloc1] * LOG2E;
    const float za = rf1a + F2MAX, zb = rf1b + F2MAX;
    const float rma = fmaxf(za, 0.2f * za), rmb = fmaxf(zb, 0.2f * zb);
    const float C1a = __builtin_amdgcn_exp2f(za - rma);
    const float C2a = __builtin_amdgcn_exp2f(0.2f * za - rma);
    const float Ta  = __builtin_amdgcn_exp2f(-za);
    const float C1b = __builtin_amdgcn_exp2f(zb - rmb);
    const float C2b = __builtin_amdgcn_exp2f(0.2f * zb - rmb);
    const float Tb  = __builtin_amdgcn_exp2f(-zb);

    // mask byte pointers (global; L2-resident, prefetched one sub-iter ahead)
    const unsigned char* mpa = maskb + (size_t)(i0 + iloc0) * 512 + jg * 128 + quad;
    const unsigned char* mpb = maskb + (size_t)(i0 + iloc1) * 512 + jg * 128 + quad;
    unsigned mA0 = mpa[0], mB0 = mpb[0];   // kb = 0
    unsigned mA1 = mpa[4], mB1 = mpb[4];   // kb = 1

    bf16x8 onesv;
#pragma unroll
    for (int i = 0; i < 8; i++) onesv[i] = (short)0x3F80;

    f32x4 acc[2][8];
#pragma unroll
    for (int f = 0; f < 2; f++)
#pragma unroll
        for (int i = 0; i < 8; i++) acc[f][i] = (f32x4){0.f, 0.f, 0.f, 0.f};
    f32x4 acc_l[2];
    acc_l[0] = (f32x4){0.f, 0.f, 0.f, 0.f};
    acc_l[1] = (f32x4){0.f, 0.f, 0.f, 0.f};

    union AF { bf16x8 v; unsigned u[4]; };
    AF af0a, af0b, af1a, af1b;

#define COMP_P(dstA, dstB, kb, mba_, mbb_)                                               \
    do {                                                                                 \
        const int jc_ = jg * 1024 + (kb) * 32 + quad * 8;                                \
        const unsigned* LA_ = &LUTM[(mba_) * 8];                                         \
        const unsigned* LB_ = &LUTM[(mbb_) * 8];                                         \
        uint4 Ma0_ = *(const uint4*)LA_;  uint4 Ma1_ = *(const uint4*)(LA_ + 4);         \
        uint4 Mb0_ = *(const uint4*)LB_;  uint4 Mb1_ = *(const uint4*)(LB_ + 4);         \
        const unsigned MA_[8] = {Ma0_.x, Ma0_.y, Ma0_.z, Ma0_.w,                         \
                                 Ma1_.x, Ma1_.y, Ma1_.z, Ma1_.w};                        \
        const unsigned MB_[8] = {Mb0_.x, Mb0_.y, Mb0_.z, Mb0_.w,                         \
                                 Mb1_.x, Mb1_.y, Mb1_.z, Mb1_.w};                        \
        _Pragma("unroll")                                                                \
        for (int t = 0; t < 8; t += 2) {                                                 \
            float4 e_ = *(const float4*)&E12[2 * (jc_ + t)];                             \
            float pa0 = ((e_.x > Ta) ? C1a : C2a) * ((e_.x > Ta) ? e_.x : e_.y);         \
            float pa1 = ((e_.z > Ta) ? C1a : C2a) * ((e_.z > Ta) ? e_.z : e_.w);         \
            float pb0 = ((e_.x > Tb) ? C1b : C2b) * ((e_.x > Tb) ? e_.x : e_.y);         \
            float pb1 = ((e_.z > Tb) ? C1b : C2b) * ((e_.z > Tb) ? e_.z : e_.w);         \
            unsigned ua0 = __float_as_uint(pa0) & MA_[t];                                \
            unsigned ua1 = __float_as_uint(pa1) & MA_[t + 1];                            \
            unsigned ub0 = __float_as_uint(pb0) & MB_[t];                                \
            unsigned ub1 = __float_as_uint(pb1) & MB_[t + 1];                            \
            dstA.u[t >> 1] = (ua0 >> 16) | ua1;                                          \
            dstB.u[t >> 1] = (ub0 >> 16) | ub1;                                          \
        }                                                                                \
    } while (0)

#define DO_MFMA(srcA, srcB, buf)                                                         \
    do {                                                                                 \
        _Pragma("unroll")                                                                \
        for (int nt = 0; nt < 8; nt++) {                                                 \
            bf16x8 bv_ = *(const bf16x8*)&Bs[buf][jg][(nt * 16 + c) * 32 + bofs];        \
            acc[0][nt] = __builtin_amdgcn_mfma_f32_16x16x32_bf16(srcA.v, bv_, acc[0][nt], 0, 0, 0); \
            acc[1][nt] = __builtin_amdgcn_mfma_f32_16x16x32_bf16(srcB.v, bv_, acc[1][nt], 0, 0, 0); \
        }                                                                                \
        acc_l[0] = __builtin_amdgcn_mfma_f32_16x16x32_bf16(srcA.v, onesv, acc_l[0], 0, 0, 0); \
        acc_l[1] = __builtin_amdgcn_mfma_f32_16x16x32_bf16(srcB.v, onesv, acc_l[1], 0, 0, 0); \
    } while (0)

    __syncthreads();              // E12 visible; tile-0 staging drained
    COMP_P(af0a, af0b, 0, mA0, mB0);

    for (int kb = 0; kb < 32; kb += 2) {
        // ---- sub-iter A: MFMA(kb, buf0) while computing P(kb+1) -> state1 ----
        ATTN_STAGE(1, kb + 1);
        if (kb + 2 < 32) { mA0 = mpa[4 * (kb + 2)]; mB0 = mpb[4 * (kb + 2)]; }
        COMP_P(af1a, af1b, kb + 1, mA1, mB1);
        DO_MFMA(af0a, af0b, 0);
        __syncthreads();
        // ---- sub-iter B: MFMA(kb+1, buf1) while computing P(kb+2) -> state0 ----
        if (kb < 30) {
            ATTN_STAGE(0, kb + 2);
            if (kb + 3 < 32) { mA1 = mpa[4 * (kb + 3)]; mB1 = mpb[4 * (kb + 3)]; }
            COMP_P(af0a, af0b, kb + 2, mA0, mB0);
        }
        DO_MFMA(af1a, af1b, 1);
        __syncthreads();
    }

    // row denominators straight from the ones-MFMA accumulators
    if (c == 0) {
#pragma unroll
        for (int f = 0; f < 2; f++)
#pragma unroll
            for (int r = 0; r < 4; r++)
                lpart[jg][rg * 32 + f * 16 + quad * 4 + r] = acc_l[f][r];
    }

    // reduce acc across j-groups into red[i][n] (i local, stride 132)
#pragma unroll
    for (int g = 0; g < 4; g++) {
        __syncthreads();
        if (jg == g) {
#pragma unroll
            for (int f = 0; f < 2; f++) {
#pragma unroll
                for (int nt = 0; nt < 8; nt++) {
#pragma unroll
                    for (int r = 0; r < 4; r++) {
                        int idx = (rg * 32 + f * 16 + quad * 4 + r) * 132 + nt * 16 + c;
                        if (g == 0) red[idx] = acc[f][nt][r];
                        else        red[idx] += acc[f][nt][r];
                    }
                }
            }
        }
    }
    __syncthreads();

    // epilogue: thread -> (row = tid>>3, two col-octets: ob and ob+8)
    const int row = tid >> 3, ob = tid & 7;
    const float l = lpart[0][row] + lpart[1][row] + lpart[2][row] + lpart[3][row];
    const float linv = 1.0f / l;
    float vv[16];
#pragma unroll
    for (int half = 0; half < 2; half++) {
#pragma unroll
        for (int t = 0; t < 8; t++) {
            float v = red[row * 132 + (ob + half * 8) * 8 + t] * linv;
            vv[half * 8 + t] = v > 0.f ? v : __expf(v) - 1.f;   // ELU
        }
    }
    const size_t obase = (size_t)(i0 + row) * ostride + h * 128 + ob * 8;
    if (F32OUT) {
        float* op = (float*)outp + obase;
        *(float4*)op = *(float4*)&vv[0];
        *(float4*)(op + 4) = *(float4*)&vv[4];
        *(float4*)(op + 64) = *(float4*)&vv[8];
        *(float4*)(op + 68) = *(float4*)&vv[12];
    } else {
        u16* op = (u16*)outp + obase;
        uint4 o;
        o.x = (unsigned)f2bf(vv[0]) | ((unsigned)f2bf(vv[1]) << 16);
        o.y = (unsigned)f2bf(vv[2]) | ((unsigned)f2bf(vv[3]) << 16);
        o.z = (unsigned)f2bf(vv[4]) | ((unsigned)f2bf(vv[5]) << 16);
        o.w = (unsigned)f2bf(vv[6]) | ((unsigned)f2bf(vv[7]) << 16);
        *(uint4*)op = o;
        o.x = (unsigned)f2bf(vv[8])  | ((unsigned)f2bf(vv[9]) << 16);
        o.y = (unsigned)f2bf(vv[10]) | ((unsigned)f2bf(vv[11]) << 16);
        o.z = (unsigned)f2bf(vv[12]) | ((unsigned)f2bf(vv[13]) << 16);
        o.w = (unsigned)f2bf(vv[14]) | ((unsigned)f2bf(vv[15]) << 16);
        *(uint4*)(op + 64) = o;
    }
}

// =====================================================================
// head_relation_combined = entity_emb[head] + relation_emb[relation] (fp32)
__global__ __launch_bounds__(256) void k_gather(const int* __restrict__ head,
                                                const int* __restrict__ rel,
                                                const float* __restrict__ ent,
                                                const float* __restrict__ rele,
                                                float* __restrict__ out) {
    int t = blockIdx.x * 256 + threadIdx.x;   // 131072 threads: row*32 + seg
    int row = t >> 5, sg = t & 31;
    int hh = head[row], rr = rel[row];
    float4 a = ((const float4*)(ent + (size_t)hh * 128))[sg];
    float4 b = ((const float4*)(rele + (size_t)rr * 128))[sg];
    float4 o;
    o.x = a.x + b.x; o.y = a.y + b.y; o.z = a.z + b.z; o.w = a.w + b.w;
    ((float4*)(out + (size_t)row * 128))[sg] = o;
}

// =====================================================================
extern "C" void kernel_launch(void* const* d_in, const int* in_sizes, int n_in,
                              void* d_out, int out_size, void* d_ws, size_t ws_size,
                              hipStream_t stream) {
    const int*   head = (const int*)d_in[0];
    const int*   rel  = (const int*)d_in[1];
    const float* adj  = (const float*)d_in[2];
    const float* ent  = (const float*)d_in[3];
    const float* rele = (const float*)d_in[4];
    const float* W0   = (const float*)d_in[5];
    const float* a0   = (const float*)d_in[6];
    const float* Wm   = (const float*)d_in[7];
    const float* am   = (const float*)d_in[8];
    const float* Wo   = (const float*)d_in[9];
    const float* ao   = (const float*)d_in[10];

    char* ws = (char*)d_ws;
    unsigned* mask = (unsigned*)(ws + 0);                 // 2 MB
    u16* WT0 = (u16*)(ws + 2097152);                      // 128 KB
    u16* WT5 = (u16*)(ws + 2228224);                      // 37 * 128 KB = 4.625 MB
    u16* WhT = (u16*)(ws + 7077888);                      // 4 MB
    float* f1 = (float*)(ws + 11272192);                  // 64 KB
    float* f2 = (float*)(ws + 11337728);                  // 64 KB
    u16* xA = (u16*)(ws + 11403264);                      // 4 MB
    u16* xB = (u16*)(ws + 15597568);                      // 4 MB
    u16* x0 = (u16*)(ws + 19791872);                      // 1 MB   (total ~20 MB)

    float* out_x = (float*)d_out;
    float* out_comb = out_x + (size_t)4096 * 128;

    k_mask<<<2048, 256, 0, stream>>>(adj, mask);
    k_cvt<<<512, 256, 0, stream>>>(ent, x0);
    k_trans<<<dim3(4, 4, 4), dim3(32, 8), 0, stream>>>(W0, WT0, 128);
    k_trans<<<dim3(16, 4, 36), dim3(32, 8), 0, stream>>>(Wm, WT5, 512);
    k_trans<<<dim3(16, 4, 1), dim3(32, 8), 0, stream>>>(Wo, WT5 + (size_t)36 * 512 * 128, 512);
    k_gather<<<512, 256, 0, stream>>>(head, rel, ent, rele, out_comb);

    // layer 0 : D -> H*D
    k_proj<<<dim3(64, 4), 1024, 0, stream>>>(x0, WT0, a0, WhT, f1, f2, 128);
    k_attn<false><<<dim3(64, 4), 512, 0, stream>>>(WhT, f1, f2, (const unsigned char*)mask, xA, 512);
    u16 *xc = xA, *xn = xB;
    // 9 middle layers : H*D -> H*D
    for (int l = 0; l < 9; l++) {
        k_proj<<<dim3(64, 4), 1024, 0, stream>>>(xc, WT5 + (size_t)l * 4 * 512 * 128,
                                                 am + (size_t)l * 4 * 256, WhT, f1, f2, 512);
        k_attn<false><<<dim3(64, 4), 512, 0, stream>>>(WhT, f1, f2, (const unsigned char*)mask, xn, 512);
        u16* t = xc; xc = xn; xn = t;
    }
    // output layer : H*D -> D, single head, fp32 out
    k_proj<<<dim3(64, 1), 1024, 0, stream>>>(xc, WT5 + (size_t)36 * 512 * 128, ao, WhT, f1, f2, 512);
    k_attn<true><<<dim3(64, 1), 512, 0, stream>>>(WhT, f1, f2, (const unsigned char*)mask, out_x, 128);
}